// Round 1
// baseline (1712.299 us; speedup 1.0000x reference)
//
#include <hip/hip_runtime.h>

constexpr int H = 4;
constexpr int F = 16;
constexpr int NODE_F = 128;
constexpr int EDGE_F = 64;
constexpr float NEG_SLOPE = 0.2f;

__device__ inline void atomicMaxF(float* addr, float val) {
    // Standard float atomic-max trick: signed max for >=0, unsigned min for <0.
    if (val >= 0.0f) atomicMax((int*)addr, __float_as_int(val));
    else             atomicMin((unsigned int*)addr, __float_as_uint(val));
}

// Fold attn vectors into the projection weights:
// Wl[k][h] = sum_f W_node[k][h*F+f] * attn_l[h][f], etc.
__global__ void fold_kernel(const float* __restrict__ Wn, const float* __restrict__ bn,
                            const float* __restrict__ Wed, const float* __restrict__ bed,
                            const float* __restrict__ al, const float* __restrict__ ar,
                            const float* __restrict__ ae,
                            float* __restrict__ Wl, float* __restrict__ Wr,
                            float* __restrict__ We, float* __restrict__ bv) {
    int idx = threadIdx.x;  // 512 threads, 1 block
    if (idx < NODE_F * H) {
        int k = idx >> 2, h = idx & 3;
        float sl = 0.f, sr = 0.f;
        #pragma unroll
        for (int f = 0; f < F; ++f) {
            float w = Wn[k * (H * F) + h * F + f];
            sl += w * al[h * F + f];
            sr += w * ar[h * F + f];
        }
        Wl[idx] = sl; Wr[idx] = sr;
    }
    if (idx < EDGE_F * H) {
        int k = idx >> 2, h = idx & 3;
        float s = 0.f;
        #pragma unroll
        for (int f = 0; f < F; ++f) s += Wed[k * (H * F) + h * F + f] * ae[h * F + f];
        We[idx] = s;
    }
    if (idx < H) {
        float sl = 0.f, sr = 0.f, se = 0.f;
        #pragma unroll
        for (int f = 0; f < F; ++f) {
            sl += bn[idx * F + f] * al[idx * F + f];
            sr += bn[idx * F + f] * ar[idx * F + f];
            se += bed[idx * F + f] * ae[idx * F + f];
        }
        bv[idx] = sl; bv[H + idx] = sr; bv[2 * H + idx] = se;
    }
}

// Per-node: el/er (folded 128x4 projection) + init emax/num/den.
__global__ void node_kernel(const float* __restrict__ nfeat,
                            const float* __restrict__ Wl, const float* __restrict__ Wr,
                            const float* __restrict__ bv,
                            float* __restrict__ el, float* __restrict__ er,
                            float* __restrict__ emax, float* __restrict__ num,
                            float* __restrict__ den, int N) {
    __shared__ float sWl[NODE_F * H];
    __shared__ float sWr[NODE_F * H];
    for (int i = threadIdx.x; i < NODE_F * H; i += blockDim.x) { sWl[i] = Wl[i]; sWr[i] = Wr[i]; }
    __syncthreads();
    int n = blockIdx.x * blockDim.x + threadIdx.x;
    if (n >= N) return;
    float accl[H] = {0.f, 0.f, 0.f, 0.f};
    float accr[H] = {0.f, 0.f, 0.f, 0.f};
    const float4* row = (const float4*)(nfeat + (size_t)n * NODE_F);
    #pragma unroll
    for (int j = 0; j < NODE_F / 4; ++j) {
        float4 v = row[j];
        #pragma unroll
        for (int h = 0; h < H; ++h) {
            accl[h] += v.x * sWl[(4 * j + 0) * H + h] + v.y * sWl[(4 * j + 1) * H + h]
                     + v.z * sWl[(4 * j + 2) * H + h] + v.w * sWl[(4 * j + 3) * H + h];
            accr[h] += v.x * sWr[(4 * j + 0) * H + h] + v.y * sWr[(4 * j + 1) * H + h]
                     + v.z * sWr[(4 * j + 2) * H + h] + v.w * sWr[(4 * j + 3) * H + h];
        }
    }
    const float NEG_INF = __int_as_float(0xff800000);
    size_t base = (size_t)n * H;
    #pragma unroll
    for (int h = 0; h < H; ++h) {
        el[base + h]   = accl[h] + bv[h];
        er[base + h]   = accr[h] + bv[H + h];
        emax[base + h] = NEG_INF;
        num[base + h]  = 0.f;
        den[base + h]  = 0.f;
    }
}

// Edge pass 1: ee = efeat . We + be ; el' = el[src] + ee ; e = leaky(el' + er[dst]);
// atomicMax emax[dst]; optionally store el'.
__global__ void edge_fwd_kernel(const float* __restrict__ efeat,
                                const int* __restrict__ src, const int* __restrict__ dst,
                                const float* __restrict__ We, const float* __restrict__ bv,
                                const float* __restrict__ el, const float* __restrict__ er,
                                float* __restrict__ emax, float* __restrict__ elp,
                                int E, int store_elp) {
    __shared__ float sWe[EDGE_F * H];
    __shared__ float sbe[H];
    for (int i = threadIdx.x; i < EDGE_F * H; i += blockDim.x) sWe[i] = We[i];
    if (threadIdx.x < H) sbe[threadIdx.x] = bv[2 * H + threadIdx.x];
    __syncthreads();
    int e = blockIdx.x * blockDim.x + threadIdx.x;
    if (e >= E) return;
    float acc[H] = {sbe[0], sbe[1], sbe[2], sbe[3]};
    const float4* row = (const float4*)(efeat + (size_t)e * EDGE_F);
    #pragma unroll
    for (int j = 0; j < EDGE_F / 4; ++j) {
        float4 v = row[j];
        #pragma unroll
        for (int h = 0; h < H; ++h) {
            acc[h] += v.x * sWe[(4 * j + 0) * H + h] + v.y * sWe[(4 * j + 1) * H + h]
                    + v.z * sWe[(4 * j + 2) * H + h] + v.w * sWe[(4 * j + 3) * H + h];
        }
    }
    int s = src[e], d = dst[e];
    float4 elv = *(const float4*)(el + (size_t)s * H);
    float4 erv = *(const float4*)(er + (size_t)d * H);
    float elp0 = elv.x + acc[0], elp1 = elv.y + acc[1], elp2 = elv.z + acc[2], elp3 = elv.w + acc[3];
    float e0 = elp0 + erv.x, e1 = elp1 + erv.y, e2 = elp2 + erv.z, e3 = elp3 + erv.w;
    e0 = e0 > 0.f ? e0 : NEG_SLOPE * e0;
    e1 = e1 > 0.f ? e1 : NEG_SLOPE * e1;
    e2 = e2 > 0.f ? e2 : NEG_SLOPE * e2;
    e3 = e3 > 0.f ? e3 : NEG_SLOPE * e3;
    float* ebase = emax + (size_t)d * H;
    atomicMaxF(ebase + 0, e0);
    atomicMaxF(ebase + 1, e1);
    atomicMaxF(ebase + 2, e2);
    atomicMaxF(ebase + 3, e3);
    if (store_elp) *(float4*)(elp + (size_t)e * H) = make_float4(elp0, elp1, elp2, elp3);
}

// Edge pass 2: ex = exp(leaky(el'+er[dst]) - emax[dst]); num[dst]+=ex*el'; den[dst]+=ex.
__global__ void edge_acc_kernel(const float* __restrict__ efeat,
                                const int* __restrict__ src, const int* __restrict__ dst,
                                const float* __restrict__ We, const float* __restrict__ bv,
                                const float* __restrict__ el, const float* __restrict__ er,
                                const float* __restrict__ emax, const float* __restrict__ elp,
                                float* __restrict__ num, float* __restrict__ den,
                                int E, int has_elp) {
    __shared__ float sWe[EDGE_F * H];
    __shared__ float sbe[H];
    for (int i = threadIdx.x; i < EDGE_F * H; i += blockDim.x) sWe[i] = We[i];
    if (threadIdx.x < H) sbe[threadIdx.x] = bv[2 * H + threadIdx.x];
    __syncthreads();
    int e = blockIdx.x * blockDim.x + threadIdx.x;
    if (e >= E) return;
    int d = dst[e];
    float elp0, elp1, elp2, elp3;
    if (has_elp) {
        float4 v = *(const float4*)(elp + (size_t)e * H);
        elp0 = v.x; elp1 = v.y; elp2 = v.z; elp3 = v.w;
    } else {
        float acc[H] = {sbe[0], sbe[1], sbe[2], sbe[3]};
        const float4* row = (const float4*)(efeat + (size_t)e * EDGE_F);
        #pragma unroll
        for (int j = 0; j < EDGE_F / 4; ++j) {
            float4 v = row[j];
            #pragma unroll
            for (int h = 0; h < H; ++h) {
                acc[h] += v.x * sWe[(4 * j + 0) * H + h] + v.y * sWe[(4 * j + 1) * H + h]
                        + v.z * sWe[(4 * j + 2) * H + h] + v.w * sWe[(4 * j + 3) * H + h];
            }
        }
        int s = src[e];
        float4 elv = *(const float4*)(el + (size_t)s * H);
        elp0 = elv.x + acc[0]; elp1 = elv.y + acc[1]; elp2 = elv.z + acc[2]; elp3 = elv.w + acc[3];
    }
    float4 erv = *(const float4*)(er + (size_t)d * H);
    float4 emv = *(const float4*)(emax + (size_t)d * H);
    float e0 = elp0 + erv.x, e1 = elp1 + erv.y, e2 = elp2 + erv.z, e3 = elp3 + erv.w;
    e0 = e0 > 0.f ? e0 : NEG_SLOPE * e0;
    e1 = e1 > 0.f ? e1 : NEG_SLOPE * e1;
    e2 = e2 > 0.f ? e2 : NEG_SLOPE * e2;
    e3 = e3 > 0.f ? e3 : NEG_SLOPE * e3;
    float x0 = expf(e0 - emv.x), x1 = expf(e1 - emv.y), x2 = expf(e2 - emv.z), x3 = expf(e3 - emv.w);
    float* nb = num + (size_t)d * H;
    float* db = den + (size_t)d * H;
    atomicAdd(nb + 0, x0 * elp0);
    atomicAdd(nb + 1, x1 * elp1);
    atomicAdd(nb + 2, x2 * elp2);
    atomicAdd(nb + 3, x3 * elp3);
    atomicAdd(db + 0, x0);
    atomicAdd(db + 1, x1);
    atomicAdd(db + 2, x2);
    atomicAdd(db + 3, x3);
}

__global__ void finalize_kernel(const float* __restrict__ num, const float* __restrict__ den,
                                float* __restrict__ out, int NH) {
    int i = blockIdx.x * blockDim.x + threadIdx.x;
    if (i < NH) {
        float d = den[i];
        out[i] = d > 0.f ? num[i] / d : 0.f;
    }
}

extern "C" void kernel_launch(void* const* d_in, const int* in_sizes, int n_in,
                              void* d_out, int out_size, void* d_ws, size_t ws_size,
                              hipStream_t stream) {
    const float* nfeat = (const float*)d_in[0];
    const float* efeat = (const float*)d_in[1];
    const float* Wn    = (const float*)d_in[2];
    const float* bn    = (const float*)d_in[3];
    const float* Wed   = (const float*)d_in[4];
    const float* bed   = (const float*)d_in[5];
    const float* al    = (const float*)d_in[6];
    const float* ar    = (const float*)d_in[7];
    const float* ae    = (const float*)d_in[8];
    const int*   src   = (const int*)d_in[9];
    const int*   dst   = (const int*)d_in[10];

    int N = in_sizes[0] / NODE_F;
    int E = in_sizes[1] / EDGE_F;

    float* ws = (float*)d_ws;
    float* Wl = ws;
    float* Wr = ws + 512;
    float* We = ws + 1024;
    float* bv = ws + 1280;  // 12 floats
    float* el   = ws + 1296;
    float* er   = el + (size_t)N * H;
    float* emax = er + (size_t)N * H;
    float* num  = emax + (size_t)N * H;
    float* den  = num + (size_t)N * H;
    float* elp  = den + (size_t)N * H;

    size_t need_full = (1296 + 5 * (size_t)N * H + (size_t)E * H) * sizeof(float);
    int use_elp = (ws_size >= need_full) ? 1 : 0;

    fold_kernel<<<1, 512, 0, stream>>>(Wn, bn, Wed, bed, al, ar, ae, Wl, Wr, We, bv);
    node_kernel<<<(N + 255) / 256, 256, 0, stream>>>(nfeat, Wl, Wr, bv, el, er, emax, num, den, N);
    edge_fwd_kernel<<<(E + 255) / 256, 256, 0, stream>>>(efeat, src, dst, We, bv, el, er,
                                                         emax, elp, E, use_elp);
    edge_acc_kernel<<<(E + 255) / 256, 256, 0, stream>>>(efeat, src, dst, We, bv, el, er,
                                                         emax, elp, num, den, E, use_elp);
    finalize_kernel<<<(N * H + 255) / 256, 256, 0, stream>>>(num, den, (float*)d_out, N * H);
}

// Round 2
// 368.548 us; speedup vs baseline: 4.6461x; 4.6461x over previous
//
#include <hip/hip_runtime.h>

constexpr int H = 4;
constexpr int F = 16;
constexpr int NODE_F = 128;
constexpr int EDGE_F = 64;
constexpr float NEG_SLOPE = 0.2f;

// ---------------- fold: Wl/Wr [128x4], We [64x4], bv[12] = biases dotted with attn ----
__global__ void fold_kernel(const float* __restrict__ Wn, const float* __restrict__ bn,
                            const float* __restrict__ Wed, const float* __restrict__ bed,
                            const float* __restrict__ al, const float* __restrict__ ar,
                            const float* __restrict__ ae,
                            float* __restrict__ Wl, float* __restrict__ Wr,
                            float* __restrict__ We, float* __restrict__ bv) {
    int idx = threadIdx.x;  // 512 threads, 1 block
    if (idx < NODE_F * H) {
        int k = idx >> 2, h = idx & 3;
        float sl = 0.f, sr = 0.f;
        #pragma unroll
        for (int f = 0; f < F; ++f) {
            float w = Wn[k * (H * F) + h * F + f];
            sl += w * al[h * F + f];
            sr += w * ar[h * F + f];
        }
        Wl[idx] = sl; Wr[idx] = sr;
    }
    if (idx < EDGE_F * H) {
        int k = idx >> 2, h = idx & 3;
        float s = 0.f;
        #pragma unroll
        for (int f = 0; f < F; ++f) s += Wed[k * (H * F) + h * F + f] * ae[h * F + f];
        We[idx] = s;
    }
    if (idx < H) {
        float sl = 0.f, sr = 0.f, se = 0.f;
        #pragma unroll
        for (int f = 0; f < F; ++f) {
            sl += bn[idx * F + f] * al[idx * F + f];
            sr += bn[idx * F + f] * ar[idx * F + f];
            se += bed[idx * F + f] * ae[idx * F + f];
        }
        bv[idx] = sl; bv[H + idx] = sr; bv[2 * H + idx] = se;
    }
}

// ---------------- node: el/er projections; zero deg (CSR) or num/den (atomic path) ----
__global__ void node_kernel(const float* __restrict__ nfeat,
                            const float* __restrict__ Wl, const float* __restrict__ Wr,
                            const float* __restrict__ bv,
                            float* __restrict__ el, float* __restrict__ er,
                            int mode, int* __restrict__ deg,
                            float* __restrict__ num, float* __restrict__ den, int N) {
    __shared__ float sWl[NODE_F * H];
    __shared__ float sWr[NODE_F * H];
    for (int i = threadIdx.x; i < NODE_F * H; i += blockDim.x) { sWl[i] = Wl[i]; sWr[i] = Wr[i]; }
    __syncthreads();
    int n = blockIdx.x * blockDim.x + threadIdx.x;
    if (n >= N) return;
    float accl[H] = {0.f, 0.f, 0.f, 0.f};
    float accr[H] = {0.f, 0.f, 0.f, 0.f};
    const float4* row = (const float4*)(nfeat + (size_t)n * NODE_F);
    #pragma unroll
    for (int j = 0; j < NODE_F / 4; ++j) {
        float4 v = row[j];
        #pragma unroll
        for (int h = 0; h < H; ++h) {
            accl[h] += v.x * sWl[(4 * j + 0) * H + h] + v.y * sWl[(4 * j + 1) * H + h]
                     + v.z * sWl[(4 * j + 2) * H + h] + v.w * sWl[(4 * j + 3) * H + h];
            accr[h] += v.x * sWr[(4 * j + 0) * H + h] + v.y * sWr[(4 * j + 1) * H + h]
                     + v.z * sWr[(4 * j + 2) * H + h] + v.w * sWr[(4 * j + 3) * H + h];
        }
    }
    size_t base = (size_t)n * H;
    *(float4*)(el + base) = make_float4(accl[0] + bv[0], accl[1] + bv[1],
                                        accl[2] + bv[2], accl[3] + bv[3]);
    *(float4*)(er + base) = make_float4(accr[0] + bv[H + 0], accr[1] + bv[H + 1],
                                        accr[2] + bv[H + 2], accr[3] + bv[H + 3]);
    if (mode == 0) {
        deg[n] = 0;
    } else {
        *(float4*)(num + base) = make_float4(0.f, 0.f, 0.f, 0.f);
        *(float4*)(den + base) = make_float4(0.f, 0.f, 0.f, 0.f);
    }
}

// ---------------- CSR path ----------------
// hist: idx[e] = slot within dst's segment (the ONLY hot-path atomics: 1.6M int adds)
__global__ void hist_kernel(const int* __restrict__ dst, int* __restrict__ deg,
                            int* __restrict__ idx, int E) {
    int e = blockIdx.x * blockDim.x + threadIdx.x;
    if (e >= E) return;
    idx[e] = atomicAdd(deg + dst[e], 1);
}

// exclusive scan of deg -> off, single block of 1024
__global__ void scan_kernel(const int* __restrict__ deg, int* __restrict__ off, int N) {
    __shared__ int part[1024];
    int t = threadIdx.x;
    int CH = (N + 1023) >> 10;
    int lo = t * CH, hi = min(lo + CH, N);
    int s = 0;
    for (int i = lo; i < hi; ++i) s += deg[i];
    part[t] = s;
    __syncthreads();
    for (int ofs = 1; ofs < 1024; ofs <<= 1) {
        int v = (t >= ofs) ? part[t - ofs] : 0;
        __syncthreads();
        part[t] += v;
        __syncthreads();
    }
    int run = (t > 0) ? part[t - 1] : 0;  // exclusive base
    for (int i = lo; i < hi; ++i) { off[i] = run; run += deg[i]; }
}

// edge scatter: stream efeat, elp = el[src] + ee, scatter 16B payload to CSR slot. No atomics.
__global__ void edge_scatter_kernel(const float* __restrict__ efeat,
                                    const int* __restrict__ src, const int* __restrict__ dst,
                                    const float* __restrict__ We, const float* __restrict__ bv,
                                    const float* __restrict__ el,
                                    const int* __restrict__ off, const int* __restrict__ idx,
                                    float* __restrict__ payload, int E) {
    __shared__ float sWe[EDGE_F * H];
    __shared__ float sbe[H];
    for (int i = threadIdx.x; i < EDGE_F * H; i += blockDim.x) sWe[i] = We[i];
    if (threadIdx.x < H) sbe[threadIdx.x] = bv[2 * H + threadIdx.x];
    __syncthreads();
    int e = blockIdx.x * blockDim.x + threadIdx.x;
    if (e >= E) return;
    float acc[H] = {sbe[0], sbe[1], sbe[2], sbe[3]};
    const float4* row = (const float4*)(efeat + (size_t)e * EDGE_F);
    #pragma unroll
    for (int j = 0; j < EDGE_F / 4; ++j) {
        float4 v = row[j];
        #pragma unroll
        for (int h = 0; h < H; ++h) {
            acc[h] += v.x * sWe[(4 * j + 0) * H + h] + v.y * sWe[(4 * j + 1) * H + h]
                    + v.z * sWe[(4 * j + 2) * H + h] + v.w * sWe[(4 * j + 3) * H + h];
        }
    }
    int s = src[e], d = dst[e];
    float4 elv = *(const float4*)(el + (size_t)s * H);
    int pos = off[d] + idx[e];
    *(float4*)(payload + (size_t)pos * 4) =
        make_float4(elv.x + acc[0], elv.y + acc[1], elv.z + acc[2], elv.w + acc[3]);
}

// node reduce: one wave per node, contiguous payload, no atomics.
// ex = exp(leaky(elp + er[d]))  (max-subtraction dropped: |e| < ~5, exp is fp32-safe)
__global__ void node_reduce_kernel(const float* __restrict__ payload,
                                   const int* __restrict__ off, const int* __restrict__ deg,
                                   const float* __restrict__ er,
                                   float* __restrict__ out, int N) {
    int wave = (int)((blockIdx.x * (size_t)blockDim.x + threadIdx.x) >> 6);
    int lane = threadIdx.x & 63;
    if (wave >= N) return;
    int o = off[wave], dg = deg[wave];
    float4 erv = *(const float4*)(er + (size_t)wave * H);
    float n0 = 0.f, n1 = 0.f, n2 = 0.f, n3 = 0.f;
    float d0 = 0.f, d1 = 0.f, d2 = 0.f, d3 = 0.f;
    for (int i = lane; i < dg; i += 64) {
        float4 p = *(const float4*)(payload + (size_t)(o + i) * 4);
        float e0 = p.x + erv.x, e1 = p.y + erv.y, e2 = p.z + erv.z, e3 = p.w + erv.w;
        e0 = e0 > 0.f ? e0 : NEG_SLOPE * e0;
        e1 = e1 > 0.f ? e1 : NEG_SLOPE * e1;
        e2 = e2 > 0.f ? e2 : NEG_SLOPE * e2;
        e3 = e3 > 0.f ? e3 : NEG_SLOPE * e3;
        float x0 = expf(e0), x1 = expf(e1), x2 = expf(e2), x3 = expf(e3);
        n0 += x0 * p.x; n1 += x1 * p.y; n2 += x2 * p.z; n3 += x3 * p.w;
        d0 += x0; d1 += x1; d2 += x2; d3 += x3;
    }
    #pragma unroll
    for (int s = 32; s; s >>= 1) {
        n0 += __shfl_down(n0, s); n1 += __shfl_down(n1, s);
        n2 += __shfl_down(n2, s); n3 += __shfl_down(n3, s);
        d0 += __shfl_down(d0, s); d1 += __shfl_down(d1, s);
        d2 += __shfl_down(d2, s); d3 += __shfl_down(d3, s);
    }
    if (lane == 0) {
        float* ob = out + (size_t)wave * H;
        ob[0] = d0 > 0.f ? n0 / d0 : 0.f;
        ob[1] = d1 > 0.f ? n1 / d1 : 0.f;
        ob[2] = d2 > 0.f ? n2 / d2 : 0.f;
        ob[3] = d3 > 0.f ? n3 / d3 : 0.f;
    }
}

// ---------------- fallback: fused single-pass atomic path (no emax) ----------------
__global__ void edge_atomic_kernel(const float* __restrict__ efeat,
                                   const int* __restrict__ src, const int* __restrict__ dst,
                                   const float* __restrict__ We, const float* __restrict__ bv,
                                   const float* __restrict__ el, const float* __restrict__ er,
                                   float* __restrict__ num, float* __restrict__ den, int E) {
    __shared__ float sWe[EDGE_F * H];
    __shared__ float sbe[H];
    for (int i = threadIdx.x; i < EDGE_F * H; i += blockDim.x) sWe[i] = We[i];
    if (threadIdx.x < H) sbe[threadIdx.x] = bv[2 * H + threadIdx.x];
    __syncthreads();
    int e = blockIdx.x * blockDim.x + threadIdx.x;
    if (e >= E) return;
    float acc[H] = {sbe[0], sbe[1], sbe[2], sbe[3]};
    const float4* row = (const float4*)(efeat + (size_t)e * EDGE_F);
    #pragma unroll
    for (int j = 0; j < EDGE_F / 4; ++j) {
        float4 v = row[j];
        #pragma unroll
        for (int h = 0; h < H; ++h) {
            acc[h] += v.x * sWe[(4 * j + 0) * H + h] + v.y * sWe[(4 * j + 1) * H + h]
                    + v.z * sWe[(4 * j + 2) * H + h] + v.w * sWe[(4 * j + 3) * H + h];
        }
    }
    int s = src[e], d = dst[e];
    float4 elv = *(const float4*)(el + (size_t)s * H);
    float4 erv = *(const float4*)(er + (size_t)d * H);
    float p0 = elv.x + acc[0], p1 = elv.y + acc[1], p2 = elv.z + acc[2], p3 = elv.w + acc[3];
    float e0 = p0 + erv.x, e1 = p1 + erv.y, e2 = p2 + erv.z, e3 = p3 + erv.w;
    e0 = e0 > 0.f ? e0 : NEG_SLOPE * e0;
    e1 = e1 > 0.f ? e1 : NEG_SLOPE * e1;
    e2 = e2 > 0.f ? e2 : NEG_SLOPE * e2;
    e3 = e3 > 0.f ? e3 : NEG_SLOPE * e3;
    float x0 = expf(e0), x1 = expf(e1), x2 = expf(e2), x3 = expf(e3);
    float* nb = num + (size_t)d * H;
    float* db = den + (size_t)d * H;
    atomicAdd(nb + 0, x0 * p0); atomicAdd(nb + 1, x1 * p1);
    atomicAdd(nb + 2, x2 * p2); atomicAdd(nb + 3, x3 * p3);
    atomicAdd(db + 0, x0); atomicAdd(db + 1, x1);
    atomicAdd(db + 2, x2); atomicAdd(db + 3, x3);
}

__global__ void finalize_kernel(const float* __restrict__ num, const float* __restrict__ den,
                                float* __restrict__ out, int NH) {
    int i = blockIdx.x * blockDim.x + threadIdx.x;
    if (i < NH) {
        float d = den[i];
        out[i] = d > 0.f ? num[i] / d : 0.f;
    }
}

extern "C" void kernel_launch(void* const* d_in, const int* in_sizes, int n_in,
                              void* d_out, int out_size, void* d_ws, size_t ws_size,
                              hipStream_t stream) {
    const float* nfeat = (const float*)d_in[0];
    const float* efeat = (const float*)d_in[1];
    const float* Wn    = (const float*)d_in[2];
    const float* bn    = (const float*)d_in[3];
    const float* Wed   = (const float*)d_in[4];
    const float* bed   = (const float*)d_in[5];
    const float* al    = (const float*)d_in[6];
    const float* ar    = (const float*)d_in[7];
    const float* ae    = (const float*)d_in[8];
    const int*   src   = (const int*)d_in[9];
    const int*   dst   = (const int*)d_in[10];

    int N = in_sizes[0] / NODE_F;
    int E = in_sizes[1] / EDGE_F;
    float* out = (float*)d_out;
    float* ws  = (float*)d_ws;

    // CSR layout (4B element offsets)
    size_t p_payload = 0;                                // E*4 floats (elp per edge, CSR order)
    size_t p_el  = p_payload + (size_t)E * 4;
    size_t p_er  = p_el + (size_t)N * H;
    size_t p_Wl  = p_er + (size_t)N * H;
    size_t p_Wr  = p_Wl + 512;
    size_t p_We  = p_Wr + 512;
    size_t p_bv  = p_We + 256;
    size_t p_deg = p_bv + 16;                            // N ints
    size_t p_off = p_deg + (size_t)N;                    // N ints
    size_t p_idx = p_off + (size_t)N;                    // E ints
    size_t csr_total = (p_idx + (size_t)E) * sizeof(float);

    if (ws_size >= csr_total) {
        float* payload = ws + p_payload;
        float* el = ws + p_el;
        float* er = ws + p_er;
        float* Wl = ws + p_Wl;
        float* Wr = ws + p_Wr;
        float* We = ws + p_We;
        float* bv = ws + p_bv;
        int* deg = (int*)(ws + p_deg);
        int* off = (int*)(ws + p_off);
        int* idx = (int*)(ws + p_idx);

        fold_kernel<<<1, 512, 0, stream>>>(Wn, bn, Wed, bed, al, ar, ae, Wl, Wr, We, bv);
        node_kernel<<<(N + 255) / 256, 256, 0, stream>>>(nfeat, Wl, Wr, bv, el, er,
                                                         0, deg, nullptr, nullptr, N);
        hist_kernel<<<(E + 255) / 256, 256, 0, stream>>>(dst, deg, idx, E);
        scan_kernel<<<1, 1024, 0, stream>>>(deg, off, N);
        edge_scatter_kernel<<<(E + 255) / 256, 256, 0, stream>>>(efeat, src, dst, We, bv, el,
                                                                 off, idx, payload, E);
        node_reduce_kernel<<<(N * 64 + 255) / 256, 256, 0, stream>>>(payload, off, deg, er,
                                                                     out, N);
    } else {
        // atomic fallback layout
        float* el  = ws;
        float* er  = el + (size_t)N * H;
        float* num = er + (size_t)N * H;
        float* den = num + (size_t)N * H;
        float* Wl  = den + (size_t)N * H;
        float* Wr  = Wl + 512;
        float* We  = Wr + 512;
        float* bv  = We + 256;

        fold_kernel<<<1, 512, 0, stream>>>(Wn, bn, Wed, bed, al, ar, ae, Wl, Wr, We, bv);
        node_kernel<<<(N + 255) / 256, 256, 0, stream>>>(nfeat, Wl, Wr, bv, el, er,
                                                         1, nullptr, num, den, N);
        edge_atomic_kernel<<<(E + 255) / 256, 256, 0, stream>>>(efeat, src, dst, We, bv,
                                                                el, er, num, den, E);
        finalize_kernel<<<(N * H + 255) / 256, 256, 0, stream>>>(num, den, out, N * H);
    }
}

// Round 3
// 179.986 us; speedup vs baseline: 9.5135x; 2.0476x over previous
//
#include <hip/hip_runtime.h>

constexpr int H = 4;
constexpr int F = 16;
constexpr int NODE_F = 128;
constexpr int EDGE_F = 64;
constexpr float NEG_SLOPE = 0.2f;

// ---------------- fold: Wl/Wr [128x4], We [64x4], bv[12]; zero the global counter ----
__global__ void fold_kernel(const float* __restrict__ Wn, const float* __restrict__ bn,
                            const float* __restrict__ Wed, const float* __restrict__ bed,
                            const float* __restrict__ al, const float* __restrict__ ar,
                            const float* __restrict__ ae,
                            float* __restrict__ Wl, float* __restrict__ Wr,
                            float* __restrict__ We, float* __restrict__ bv,
                            int* __restrict__ total) {
    int idx = threadIdx.x;  // 512 threads, 1 block
    if (idx == 0) *total = 0;
    if (idx < NODE_F * H) {
        int k = idx >> 2, h = idx & 3;
        float sl = 0.f, sr = 0.f;
        #pragma unroll
        for (int f = 0; f < F; ++f) {
            float w = Wn[k * (H * F) + h * F + f];
            sl += w * al[h * F + f];
            sr += w * ar[h * F + f];
        }
        Wl[idx] = sl; Wr[idx] = sr;
    }
    if (idx < EDGE_F * H) {
        int k = idx >> 2, h = idx & 3;
        float s = 0.f;
        #pragma unroll
        for (int f = 0; f < F; ++f) s += Wed[k * (H * F) + h * F + f] * ae[h * F + f];
        We[idx] = s;
    }
    if (idx < H) {
        float sl = 0.f, sr = 0.f, se = 0.f;
        #pragma unroll
        for (int f = 0; f < F; ++f) {
            sl += bn[idx * F + f] * al[idx * F + f];
            sr += bn[idx * F + f] * ar[idx * F + f];
            se += bed[idx * F + f] * ae[idx * F + f];
        }
        bv[idx] = sl; bv[H + idx] = sr; bv[2 * H + idx] = se;
    }
}

// ---------------- node proj: 4 lanes per node, coalesced 64B-line reads ----
__global__ void node_proj_kernel(const float* __restrict__ nfeat,
                                 const float* __restrict__ Wl, const float* __restrict__ Wr,
                                 const float* __restrict__ bv,
                                 float* __restrict__ el, float* __restrict__ er,
                                 int* __restrict__ deg, int N) {
    __shared__ float sWl[NODE_F * H];
    __shared__ float sWr[NODE_F * H];
    for (int i = threadIdx.x; i < NODE_F * H; i += blockDim.x) { sWl[i] = Wl[i]; sWr[i] = Wr[i]; }
    __syncthreads();
    int lane = threadIdx.x & 63;
    int wave = (int)(((size_t)blockIdx.x * blockDim.x + threadIdx.x) >> 6);
    int sub = lane & 3, ln = lane >> 2;
    int n = wave * 16 + ln;
    if (n >= N) return;
    float accl[H] = {0.f, 0.f, 0.f, 0.f};
    float accr[H] = {0.f, 0.f, 0.f, 0.f};
    const float4* row = (const float4*)(nfeat + (size_t)n * NODE_F);
    #pragma unroll
    for (int i = 0; i < 8; ++i) {
        float4 v = row[sub + 4 * i];
        int k0 = (sub + 4 * i) * 4;
        #pragma unroll
        for (int h = 0; h < H; ++h) {
            accl[h] += v.x * sWl[(k0 + 0) * H + h] + v.y * sWl[(k0 + 1) * H + h]
                     + v.z * sWl[(k0 + 2) * H + h] + v.w * sWl[(k0 + 3) * H + h];
            accr[h] += v.x * sWr[(k0 + 0) * H + h] + v.y * sWr[(k0 + 1) * H + h]
                     + v.z * sWr[(k0 + 2) * H + h] + v.w * sWr[(k0 + 3) * H + h];
        }
    }
    #pragma unroll
    for (int m = 1; m < 4; m <<= 1) {
        #pragma unroll
        for (int h = 0; h < H; ++h) {
            accl[h] += __shfl_xor(accl[h], m);
            accr[h] += __shfl_xor(accr[h], m);
        }
    }
    el[(size_t)n * H + sub] = accl[sub] + bv[sub];
    er[(size_t)n * H + sub] = accr[sub] + bv[H + sub];
    if (sub == 0) deg[n] = 0;
}

// ---------------- edge proj + hist: 4 lanes/edge; payload in EDGE order (coalesced write) ----
__global__ void edge_proj_kernel(const float* __restrict__ efeat,
                                 const int* __restrict__ src, const int* __restrict__ dst,
                                 const float* __restrict__ We, const float* __restrict__ bv,
                                 const float* __restrict__ el,
                                 float* __restrict__ payload, int* __restrict__ idx,
                                 int* __restrict__ deg, int E) {
    __shared__ float sWe[EDGE_F * H];
    __shared__ float sbe[H];
    for (int i = threadIdx.x; i < EDGE_F * H; i += blockDim.x) sWe[i] = We[i];
    if (threadIdx.x < H) sbe[threadIdx.x] = bv[2 * H + threadIdx.x];
    __syncthreads();
    int lane = threadIdx.x & 63;
    int wave = (int)(((size_t)blockIdx.x * blockDim.x + threadIdx.x) >> 6);
    int sub = lane & 3, le = lane >> 2;
    int e = wave * 16 + le;
    if (e >= E) return;
    float acc[H] = {0.f, 0.f, 0.f, 0.f};
    const float4* row = (const float4*)(efeat + (size_t)e * EDGE_F);
    #pragma unroll
    for (int i = 0; i < 4; ++i) {
        float4 v = row[sub + 4 * i];
        int k0 = (sub + 4 * i) * 4;
        #pragma unroll
        for (int h = 0; h < H; ++h) {
            acc[h] += v.x * sWe[(k0 + 0) * H + h] + v.y * sWe[(k0 + 1) * H + h]
                    + v.z * sWe[(k0 + 2) * H + h] + v.w * sWe[(k0 + 3) * H + h];
        }
    }
    #pragma unroll
    for (int m = 1; m < 4; m <<= 1) {
        #pragma unroll
        for (int h = 0; h < H; ++h) acc[h] += __shfl_xor(acc[h], m);
    }
    int s = src[e];
    payload[(size_t)e * H + sub] = el[(size_t)s * H + sub] + acc[sub] + sbe[sub];
    if (sub == 0) idx[e] = atomicAdd(deg + dst[e], 1);
}

// ---------------- offsets: wave-scan + one atomic per wave (segment order run-varying,
// per-node contents identical — same class as hist atomics) ----
__global__ void offsets_kernel(const int* __restrict__ deg, int* __restrict__ off,
                               int* __restrict__ total, int N) {
    int lane = threadIdx.x & 63;
    int gid = blockIdx.x * blockDim.x + threadIdx.x;
    int x = (gid < N) ? deg[gid] : 0;
    int incl = x;
    #pragma unroll
    for (int s = 1; s < 64; s <<= 1) {
        int y = __shfl_up(incl, s);
        if (lane >= s) incl += y;
    }
    int wtot = __shfl(incl, 63);
    int base = 0;
    if (lane == 63) base = atomicAdd(total, wtot);
    base = __shfl(base, 63);
    if (gid < N) off[gid] = base + incl - x;
}

// ---------------- scatter edge ids into CSR slots (4B random writes, L2-resident) ----
__global__ void scatter_eid_kernel(const int* __restrict__ dst, const int* __restrict__ idx,
                                   const int* __restrict__ off, int* __restrict__ eid, int E) {
    int e = blockIdx.x * blockDim.x + threadIdx.x;
    if (e >= E) return;
    eid[off[dst[e]] + idx[e]] = e;
}

// ---------------- node reduce: 16 lanes per node, gather payload (L2/L3-resident) ----
__global__ void node_reduce_kernel(const float* __restrict__ payload,
                                   const int* __restrict__ eid,
                                   const int* __restrict__ off, const int* __restrict__ deg,
                                   const float* __restrict__ er,
                                   float* __restrict__ out, int N) {
    int lane = threadIdx.x & 63;
    int wave = (int)(((size_t)blockIdx.x * blockDim.x + threadIdx.x) >> 6);
    int g = lane >> 4;            // group 0..3 within wave
    int gl = lane & 15;           // lane within group
    int n = wave * 4 + g;
    if (n >= N) return;
    int o = off[n], dg = deg[n];
    float4 erv = *(const float4*)(er + (size_t)n * H);
    float n0 = 0.f, n1 = 0.f, n2 = 0.f, n3 = 0.f;
    float d0 = 0.f, d1 = 0.f, d2 = 0.f, d3 = 0.f;
    for (int i = gl; i < dg; i += 16) {
        int ee = eid[o + i];
        float4 p = *(const float4*)(payload + (size_t)ee * H);
        float e0 = p.x + erv.x, e1 = p.y + erv.y, e2 = p.z + erv.z, e3 = p.w + erv.w;
        e0 = e0 > 0.f ? e0 : NEG_SLOPE * e0;
        e1 = e1 > 0.f ? e1 : NEG_SLOPE * e1;
        e2 = e2 > 0.f ? e2 : NEG_SLOPE * e2;
        e3 = e3 > 0.f ? e3 : NEG_SLOPE * e3;
        float x0 = expf(e0), x1 = expf(e1), x2 = expf(e2), x3 = expf(e3);
        n0 += x0 * p.x; n1 += x1 * p.y; n2 += x2 * p.z; n3 += x3 * p.w;
        d0 += x0; d1 += x1; d2 += x2; d3 += x3;
    }
    #pragma unroll
    for (int s = 8; s; s >>= 1) {
        n0 += __shfl_down(n0, s, 16); n1 += __shfl_down(n1, s, 16);
        n2 += __shfl_down(n2, s, 16); n3 += __shfl_down(n3, s, 16);
        d0 += __shfl_down(d0, s, 16); d1 += __shfl_down(d1, s, 16);
        d2 += __shfl_down(d2, s, 16); d3 += __shfl_down(d3, s, 16);
    }
    if (gl == 0) {
        *(float4*)(out + (size_t)n * H) =
            make_float4(d0 > 0.f ? n0 / d0 : 0.f, d1 > 0.f ? n1 / d1 : 0.f,
                        d2 > 0.f ? n2 / d2 : 0.f, d3 > 0.f ? n3 / d3 : 0.f);
    }
}

// ---------------- fallback (small ws): fused atomic path ----
__global__ void zero_kernel(float* __restrict__ p, int n) {
    int i = blockIdx.x * blockDim.x + threadIdx.x;
    if (i < n) p[i] = 0.f;
}

__global__ void edge_atomic_kernel(const float* __restrict__ efeat,
                                   const int* __restrict__ src, const int* __restrict__ dst,
                                   const float* __restrict__ We, const float* __restrict__ bv,
                                   const float* __restrict__ el, const float* __restrict__ er,
                                   float* __restrict__ num, float* __restrict__ den, int E) {
    __shared__ float sWe[EDGE_F * H];
    __shared__ float sbe[H];
    for (int i = threadIdx.x; i < EDGE_F * H; i += blockDim.x) sWe[i] = We[i];
    if (threadIdx.x < H) sbe[threadIdx.x] = bv[2 * H + threadIdx.x];
    __syncthreads();
    int e = blockIdx.x * blockDim.x + threadIdx.x;
    if (e >= E) return;
    float acc[H] = {sbe[0], sbe[1], sbe[2], sbe[3]};
    const float4* row = (const float4*)(efeat + (size_t)e * EDGE_F);
    #pragma unroll
    for (int j = 0; j < EDGE_F / 4; ++j) {
        float4 v = row[j];
        #pragma unroll
        for (int h = 0; h < H; ++h) {
            acc[h] += v.x * sWe[(4 * j + 0) * H + h] + v.y * sWe[(4 * j + 1) * H + h]
                    + v.z * sWe[(4 * j + 2) * H + h] + v.w * sWe[(4 * j + 3) * H + h];
        }
    }
    int s = src[e], d = dst[e];
    float4 elv = *(const float4*)(el + (size_t)s * H);
    float4 erv = *(const float4*)(er + (size_t)d * H);
    float p0 = elv.x + acc[0], p1 = elv.y + acc[1], p2 = elv.z + acc[2], p3 = elv.w + acc[3];
    float e0 = p0 + erv.x, e1 = p1 + erv.y, e2 = p2 + erv.z, e3 = p3 + erv.w;
    e0 = e0 > 0.f ? e0 : NEG_SLOPE * e0;
    e1 = e1 > 0.f ? e1 : NEG_SLOPE * e1;
    e2 = e2 > 0.f ? e2 : NEG_SLOPE * e2;
    e3 = e3 > 0.f ? e3 : NEG_SLOPE * e3;
    float x0 = expf(e0), x1 = expf(e1), x2 = expf(e2), x3 = expf(e3);
    float* nb = num + (size_t)d * H;
    float* db = den + (size_t)d * H;
    atomicAdd(nb + 0, x0 * p0); atomicAdd(nb + 1, x1 * p1);
    atomicAdd(nb + 2, x2 * p2); atomicAdd(nb + 3, x3 * p3);
    atomicAdd(db + 0, x0); atomicAdd(db + 1, x1);
    atomicAdd(db + 2, x2); atomicAdd(db + 3, x3);
}

__global__ void finalize_kernel(const float* __restrict__ num, const float* __restrict__ den,
                                float* __restrict__ out, int NH) {
    int i = blockIdx.x * blockDim.x + threadIdx.x;
    if (i < NH) {
        float d = den[i];
        out[i] = d > 0.f ? num[i] / d : 0.f;
    }
}

extern "C" void kernel_launch(void* const* d_in, const int* in_sizes, int n_in,
                              void* d_out, int out_size, void* d_ws, size_t ws_size,
                              hipStream_t stream) {
    const float* nfeat = (const float*)d_in[0];
    const float* efeat = (const float*)d_in[1];
    const float* Wn    = (const float*)d_in[2];
    const float* bn    = (const float*)d_in[3];
    const float* Wed   = (const float*)d_in[4];
    const float* bed   = (const float*)d_in[5];
    const float* al    = (const float*)d_in[6];
    const float* ar    = (const float*)d_in[7];
    const float* ae    = (const float*)d_in[8];
    const int*   src   = (const int*)d_in[9];
    const int*   dst   = (const int*)d_in[10];

    int N = in_sizes[0] / NODE_F;
    int E = in_sizes[1] / EDGE_F;
    float* out = (float*)d_out;
    float* ws  = (float*)d_ws;

    // CSR layout (float-element offsets; all 16B aligned)
    size_t p_payload = 0;                    // E*4 floats, edge order
    size_t p_el   = p_payload + (size_t)E * 4;
    size_t p_er   = p_el + (size_t)N * H;
    size_t p_Wl   = p_er + (size_t)N * H;
    size_t p_Wr   = p_Wl + 512;
    size_t p_We   = p_Wr + 512;
    size_t p_bv   = p_We + 256;
    size_t p_tot  = p_bv + 16;               // 1 int (+pad)
    size_t p_deg  = p_tot + 16;              // N ints
    size_t p_off  = p_deg + (size_t)N;       // N ints
    size_t p_idx  = p_off + (size_t)N;       // E ints
    size_t p_eid  = p_idx + (size_t)E;       // E ints
    size_t csr_total = (p_eid + (size_t)E) * sizeof(float);

    if (ws_size >= csr_total) {
        float* payload = ws + p_payload;
        float* el = ws + p_el;
        float* er = ws + p_er;
        float* Wl = ws + p_Wl;
        float* Wr = ws + p_Wr;
        float* We = ws + p_We;
        float* bv = ws + p_bv;
        int* total = (int*)(ws + p_tot);
        int* deg = (int*)(ws + p_deg);
        int* off = (int*)(ws + p_off);
        int* idx = (int*)(ws + p_idx);
        int* eid = (int*)(ws + p_eid);

        fold_kernel<<<1, 512, 0, stream>>>(Wn, bn, Wed, bed, al, ar, ae, Wl, Wr, We, bv, total);
        node_proj_kernel<<<(int)(((size_t)N * 4 + 255) / 256), 256, 0, stream>>>(
            nfeat, Wl, Wr, bv, el, er, deg, N);
        edge_proj_kernel<<<(int)(((size_t)E * 4 + 255) / 256), 256, 0, stream>>>(
            efeat, src, dst, We, bv, el, payload, idx, deg, E);
        offsets_kernel<<<(N + 255) / 256, 256, 0, stream>>>(deg, off, total, N);
        scatter_eid_kernel<<<(E + 255) / 256, 256, 0, stream>>>(dst, idx, off, eid, E);
        node_reduce_kernel<<<(int)(((size_t)N * 16 + 255) / 256), 256, 0, stream>>>(
            payload, eid, off, deg, er, out, N);
    } else {
        // atomic fallback layout
        float* el  = ws;
        float* er  = el + (size_t)N * H;
        float* num = er + (size_t)N * H;
        float* den = num + (size_t)N * H;
        float* Wl  = den + (size_t)N * H;
        float* Wr  = Wl + 512;
        float* We  = Wr + 512;
        float* bv  = We + 256;
        int* total = (int*)(bv + 16);
        int* deg   = total + 16;  // reused as scratch; zeroed but unused further

        fold_kernel<<<1, 512, 0, stream>>>(Wn, bn, Wed, bed, al, ar, ae, Wl, Wr, We, bv, total);
        node_proj_kernel<<<(int)(((size_t)N * 4 + 255) / 256), 256, 0, stream>>>(
            nfeat, Wl, Wr, bv, el, er, deg, N);
        zero_kernel<<<(int)(((size_t)N * 2 * H + 255) / 256), 256, 0, stream>>>(num, N * 2 * H);
        edge_atomic_kernel<<<(E + 255) / 256, 256, 0, stream>>>(efeat, src, dst, We, bv,
                                                                el, er, num, den, E);
        finalize_kernel<<<(N * H + 255) / 256, 256, 0, stream>>>(num, den, out, N * H);
    }
}